// Round 11
// baseline (5201.014 us; speedup 1.0000x reference)
//
#include <hip/hip_runtime.h>
#include <cstdint>
#include <cstddef>

#define SEQ 256
#define BATCH 128
#define HID 1024
#define H3 3072
#define MEGA (SEQ + 2)          // 258 mega-steps
#define HSLOT 32768             // u64 granules per h slot (128*1024/4)
#define GSLOT 393216            // f32 per gi slot (64ct * 48 * 128)

typedef __bf16 bf16x8 __attribute__((ext_vector_type(8)));
typedef float f32x4 __attribute__((ext_vector_type(4)));
typedef unsigned short ushort8 __attribute__((ext_vector_type(8)));
typedef unsigned long long u64x2 __attribute__((ext_vector_type(2)));

static __device__ __forceinline__ unsigned short f2bf(float f){
  unsigned int u = __float_as_uint(f);
  u += 0x7fffu + ((u >> 16) & 1u);
  return (unsigned short)(u >> 16);
}
static __device__ __forceinline__ float sigm(float x){
  return 1.0f / (1.0f + __expf(-x));
}
static __device__ __forceinline__ float tanh_(float x){
  x = fminf(15.0f, fmaxf(-15.0f, x));
  float e = __expf(2.0f * x);
  return (e - 1.0f) / (e + 1.0f);
}
static __device__ __forceinline__ unsigned ald(const unsigned* p){
  return __hip_atomic_load(p, __ATOMIC_RELAXED, __HIP_MEMORY_SCOPE_AGENT);
}
static __device__ __forceinline__ unsigned long long ald64(const unsigned long long* p){
  return __hip_atomic_load(p, __ATOMIC_RELAXED, __HIP_MEMORY_SCOPE_AGENT);
}
static __device__ __forceinline__ void ast64(unsigned long long* p, unsigned long long v){
  __hip_atomic_store(p, v, __ATOMIC_RELAXED, __HIP_MEMORY_SCOPE_AGENT);
}

// ---------------- prologue kernels ----------------

__global__ __launch_bounds__(256) void cvt_bf16(const float* __restrict__ in,
                                                unsigned short* __restrict__ out, int n4){
  int i = blockIdx.x * blockDim.x + threadIdx.x;
  int stride = gridDim.x * blockDim.x;
  for (; i < n4; i += stride){
    float4 v = reinterpret_cast<const float4*>(in)[i];
    ushort4 o = { f2bf(v.x), f2bf(v.y), f2bf(v.z), f2bf(v.w) };
    reinterpret_cast<ushort4*>(out)[i] = o;
  }
}

__global__ __launch_bounds__(256) void embed_gather(const int* __restrict__ src,
                                                    const float* __restrict__ embW,
                                                    unsigned short* __restrict__ x0){
  int bx = blockIdx.x;            // = s*BATCH + b
  int s = bx >> 7, b = bx & 127;
  int row = src[b * SEQ + s];
  float4 v = reinterpret_cast<const float4*>(embW + (size_t)row * HID)[threadIdx.x];
  ushort4 o = { f2bf(v.x), f2bf(v.y), f2bf(v.z), f2bf(v.w) };
  reinterpret_cast<ushort4*>(x0 + (size_t)bx * HID)[threadIdx.x] = o;
}

__global__ __launch_bounds__(256) void zero_u32(unsigned* __restrict__ p, int n){
  int i = blockIdx.x * blockDim.x + threadIdx.x;
  if (i < n) p[i] = 0u;
}

// ---------------- fused persistent kernel helpers ----------------

// 128x(16x3)x1024 GEMM, A = bf16 h-ring (u64 granules, atomic loads).
// Wave w owns rows [w*32, w*32+32) (2 rowtiles), full K. acc[rt][gate].
static __device__ __forceinline__ void gemm_ring(
    const unsigned long long* __restrict__ Asrc,
    const unsigned short* __restrict__ wbase,   // Wlds + lane*8
    int w, int lane, f32x4 acc[2][3])
{
  int fr = lane & 15, kg = lane >> 4;
  #pragma unroll
  for (int rt = 0; rt < 2; ++rt){
    size_t ab = (size_t)(w*32 + rt*16 + fr) * 256 + kg * 2;
    bf16x8 A0[8], A1[8];
    #pragma unroll
    for (int j = 0; j < 8; ++j){
      u64x2 uu; uu[0] = ald64(Asrc + ab + j*8); uu[1] = ald64(Asrc + ab + j*8 + 1);
      A0[j] = __builtin_bit_cast(bf16x8, uu);
    }
    #pragma unroll
    for (int blk = 0; blk < 4; ++blk){
      if (blk < 3){
        bf16x8* dst = (blk & 1) ? A0 : A1;
        #pragma unroll
        for (int j = 0; j < 8; ++j){
          size_t o = ab + (size_t)(blk + 1) * 64 + j * 8;
          u64x2 uu; uu[0] = ald64(Asrc + o); uu[1] = ald64(Asrc + o + 1);
          dst[j] = __builtin_bit_cast(bf16x8, uu);
        }
      }
      const bf16x8* cur = (blk & 1) ? A1 : A0;
      #pragma unroll
      for (int j = 0; j < 8; ++j){
        int ks = blk*8 + j;
        bf16x8 b0 = *(const bf16x8*)(wbase + (size_t)(     ks) * 512);
        bf16x8 b1 = *(const bf16x8*)(wbase + (size_t)(32 + ks) * 512);
        bf16x8 b2 = *(const bf16x8*)(wbase + (size_t)(64 + ks) * 512);
        acc[rt][0] = __builtin_amdgcn_mfma_f32_16x16x32_bf16(cur[j], b0, acc[rt][0], 0,0,0);
        acc[rt][1] = __builtin_amdgcn_mfma_f32_16x16x32_bf16(cur[j], b1, acc[rt][1], 0,0,0);
        acc[rt][2] = __builtin_amdgcn_mfma_f32_16x16x32_bf16(cur[j], b2, acc[rt][2], 0,0,0);
      }
    }
  }
}

// same GEMM but A = plain bf16 rows (x0; each element read once -> plain loads)
static __device__ __forceinline__ void gemm_x0(
    const unsigned short* __restrict__ Arows,   // base of 128 rows
    const unsigned short* __restrict__ wbase,
    int w, int lane, f32x4 acc[2][3])
{
  int fr = lane & 15, kg = lane >> 4;
  #pragma unroll
  for (int rt = 0; rt < 2; ++rt){
    const unsigned short* ap = Arows + (size_t)(w*32 + rt*16 + fr) * HID + kg * 8;
    bf16x8 A0[8], A1[8];
    #pragma unroll
    for (int j = 0; j < 8; ++j) A0[j] = *(const bf16x8*)(ap + j * 32);
    #pragma unroll
    for (int blk = 0; blk < 4; ++blk){
      if (blk < 3){
        bf16x8* dst = (blk & 1) ? A0 : A1;
        #pragma unroll
        for (int j = 0; j < 8; ++j)
          dst[j] = *(const bf16x8*)(ap + (blk + 1) * 256 + j * 32);
      }
      const bf16x8* cur = (blk & 1) ? A1 : A0;
      #pragma unroll
      for (int j = 0; j < 8; ++j){
        int ks = blk*8 + j;
        bf16x8 b0 = *(const bf16x8*)(wbase + (size_t)(     ks) * 512);
        bf16x8 b1 = *(const bf16x8*)(wbase + (size_t)(32 + ks) * 512);
        bf16x8 b2 = *(const bf16x8*)(wbase + (size_t)(64 + ks) * 512);
        acc[rt][0] = __builtin_amdgcn_mfma_f32_16x16x32_bf16(cur[j], b0, acc[rt][0], 0,0,0);
        acc[rt][1] = __builtin_amdgcn_mfma_f32_16x16x32_bf16(cur[j], b1, acc[rt][1], 0,0,0);
        acc[rt][2] = __builtin_amdgcn_mfma_f32_16x16x32_bf16(cur[j], b2, acc[rt][2], 0,0,0);
      }
    }
  }
}

// store raw f32 acc -> gi ring slot (layout [ct][g*16+col][128 rows])
static __device__ __forceinline__ void store_gi(
    float* __restrict__ dst, int w, int lane, const f32x4 acc[2][3])
{
  int fr = lane & 15, kg = lane >> 4;
  #pragma unroll
  for (int rt = 0; rt < 2; ++rt)
    #pragma unroll
    for (int g = 0; g < 3; ++g){
      f32x4 v = acc[rt][g];
      u64x2 uu = __builtin_bit_cast(u64x2, v);
      size_t o = ((size_t)(g*16 + fr)) * 128 + w*32 + rt*16 + kg*4;
      unsigned long long* p = (unsigned long long*)(dst + o);
      ast64(p, uu[0]); ast64(p + 1, uu[1]);
    }
}

static __device__ __forceinline__ void load_gi(
    const float* __restrict__ src, int w, int lane, f32x4 g[2][3])
{
  int fr = lane & 15, kg = lane >> 4;
  #pragma unroll
  for (int rt = 0; rt < 2; ++rt)
    #pragma unroll
    for (int gg = 0; gg < 3; ++gg){
      size_t o = ((size_t)(gg*16 + fr)) * 128 + w*32 + rt*16 + kg*4;
      const unsigned long long* p = (const unsigned long long*)(src + o);
      u64x2 uu; uu[0] = ald64(p); uu[1] = ald64(p + 1);
      g[rt][gg] = __builtin_bit_cast(f32x4, uu);
    }
}

// publish bf16 h tile (wave-local transpose through LDS, then u64 atomics)
static __device__ __forceinline__ void publish_h(
    unsigned long long* __restrict__ dst,       // h ring slot base
    unsigned short (*hvt)[16][16],              // this wave's [2][16][16]
    int w, int lane, int ct, const f32x4 h[2])
{
  int fr = lane & 15, kg = lane >> 4;
  #pragma unroll
  for (int rt = 0; rt < 2; ++rt)
    #pragma unroll
    for (int q = 0; q < 4; ++q)
      hvt[rt][kg*4 + q][fr] = f2bf(h[rt][q]);
  asm volatile("s_waitcnt lgkmcnt(0)" ::: "memory");
  __builtin_amdgcn_sched_barrier(0);
  int rt2 = lane >> 5, idx = lane & 31, rr = idx >> 1, c8 = (idx & 1) * 8;
  ushort8 hv = *(const ushort8*)&hvt[rt2][rr][c8];
  u64x2 uu = __builtin_bit_cast(u64x2, hv);
  size_t ui = (size_t)(w*32 + rt2*16 + rr) * 256 + ct*4 + (c8 >> 2);
  ast64(dst + ui, uu[0]); ast64(dst + ui + 1, uu[1]);
}

// ---------------- fused persistent kernel ----------------
// 256 WGs x 256 thr. part = blockIdx.x>>6 (0=a h0-chain, 1=b gi1, 2=c h1-chain,
// 3=d gi0 look-ahead); ct = blockIdx.x&63 (16-col x 3-gate tile).
// Each WG: 128 rows, full-K waves (no reduction). Weights staged once.
__global__ __launch_bounds__(256) void gru_fused(
    const unsigned short* __restrict__ wih0b,
    const unsigned short* __restrict__ whh0b,
    const unsigned short* __restrict__ wih1b,
    const unsigned short* __restrict__ whh1b,
    const float* __restrict__ bih,              // [2][3072]
    const float* __restrict__ bhh,
    const unsigned short* __restrict__ x0,      // [SEQ*BATCH][HID] bf16
    float* __restrict__ gi0r,                   // 8 slots x GSLOT
    float* __restrict__ gi1r,                   // 8 slots x GSLOT
    unsigned long long* __restrict__ h0r,       // 4 slots x HSLOT
    unsigned long long* __restrict__ h1r,       // 2 slots x HSLOT
    float* __restrict__ out,
    unsigned* __restrict__ f0, unsigned* __restrict__ fB,
    unsigned* __restrict__ f1, unsigned* __restrict__ fD)
{
  __shared__ unsigned short Wlds[48 * 1024];    // 96 KB fragment-order
  __shared__ unsigned short hvt[4][2][16][16];  // 4 KB per-wave transpose

  int tid = threadIdx.x, lane = tid & 63, w = tid >> 6;
  int part = blockIdx.x >> 6, ct = blockIdx.x & 63;
  int fr = lane & 15, kg = lane >> 4;
  int c0 = ct * 16;

  const unsigned short* wsrc =
      (part == 0) ? whh0b : (part == 1) ? wih1b : (part == 2) ? whh1b : wih0b;
  #pragma unroll
  for (int j = 0; j < 24; ++j){
    int cid = j * 256 + tid;
    int rr = cid & 15, sl = (cid >> 4) & 127, g = cid >> 11;
    int ks = sl >> 2, kgs = sl & 3;
    int ldso = ((g*32 + ks)*64 + kgs*16 + rr) * 8;
    int grow = g * HID + c0 + rr;
    *(ushort8*)&Wlds[ldso] = *(const ushort8*)(wsrc + (size_t)grow * HID + sl*8);
  }

  int col = c0 + fr;
  float br_ = 0.f, bz_ = 0.f, bi_ = 0.f, bh_ = 0.f;
  if (part == 0 || part == 2){
    const float* bl = bih + (part == 2 ? H3 : 0);
    const float* bh2 = bhh + (part == 2 ? H3 : 0);
    br_ = bl[col] + bh2[col];
    bz_ = bl[HID + col] + bh2[HID + col];
    bi_ = bl[2*HID + col];
    bh_ = bh2[2*HID + col];
  }
  f32x4 hp[2] = {f32x4{0,0,0,0}, f32x4{0,0,0,0}};
  const unsigned short* wbase = Wlds + lane * 8;
  float* state = out + (size_t)SEQ * BATCH * HID;

  __syncthreads();   // weights staged

  if (part == 0){
    // ---------- (a): h0 recurrence chain ----------
    for (int m = 0; m <= SEQ - 1; ++m){
      if (w == 0){
        const unsigned* pD = fD + (size_t)m * 64 + ct;
        const unsigned* p0 = f0 + (size_t)(m - 1) * 64;
        const unsigned* pB = fB + (size_t)(m - 4) * 64;
        int lim = 50000000;
        for (;;){
          unsigned vD = ald(pD);
          unsigned v0 = (m >= 1) ? ald(p0 + lane) : 1u;
          unsigned vB = (m >= 4) ? ald(pB + lane) : 1u;
          if (__all((vD & v0 & vB) != 0) || !--lim) break;
          __builtin_amdgcn_s_sleep(1);
        }
      }
      __syncthreads();
      asm volatile("" ::: "memory");

      f32x4 acc[2][3] = {};
      if (m >= 1) gemm_ring(h0r + (size_t)((m - 1) & 3) * HSLOT, wbase, w, lane, acc);
      f32x4 g0[2][3];
      load_gi(gi0r + ((size_t)(m & 7) * 64 + ct) * 6144, w, lane, g0);

      f32x4 h[2];
      #pragma unroll
      for (int rt = 0; rt < 2; ++rt)
        #pragma unroll
        for (int q = 0; q < 4; ++q){
          float r = sigm(g0[rt][0][q] + acc[rt][0][q] + br_);
          float z = sigm(g0[rt][1][q] + acc[rt][1][q] + bz_);
          float n = tanh_(g0[rt][2][q] + bi_ + r * (acc[rt][2][q] + bh_));
          h[rt][q] = (1.0f - z) * n + z * hp[rt][q];
        }
      hp[0] = h[0]; hp[1] = h[1];

      publish_h(h0r + (size_t)(m & 3) * HSLOT, hvt[w], w, lane, ct, h);
      asm volatile("s_waitcnt vmcnt(0)" ::: "memory");
      __syncthreads();
      if (tid == 0)
        __hip_atomic_store(f0 + (size_t)m * 64 + ct, 1u,
                           __ATOMIC_RELAXED, __HIP_MEMORY_SCOPE_AGENT);
    }
    #pragma unroll
    for (int rt = 0; rt < 2; ++rt)
      #pragma unroll
      for (int q = 0; q < 4; ++q)
        state[(size_t)(w*32 + rt*16 + kg*4 + q) * HID + col] = hp[rt][q];

  } else if (part == 1){
    // ---------- (b): gi1[m-1] = h0[m-1] @ Wih1^T ----------
    for (int m = 1; m <= SEQ; ++m){
      if (w == 0){
        const unsigned* p0 = f0 + (size_t)(m - 1) * 64;
        const unsigned* p1 = f1 + (size_t)(m - 9) * 64 + ct;
        int lim = 50000000;
        for (;;){
          unsigned v0 = ald(p0 + lane);
          unsigned v1 = (m >= 9) ? ald(p1) : 1u;
          if (__all((v0 & v1) != 0) || !--lim) break;
          __builtin_amdgcn_s_sleep(1);
        }
      }
      __syncthreads();
      asm volatile("" ::: "memory");

      f32x4 acc[2][3] = {};
      gemm_ring(h0r + (size_t)((m - 1) & 3) * HSLOT, wbase, w, lane, acc);
      store_gi(gi1r + ((size_t)((m - 1) & 7) * 64 + ct) * 6144, w, lane, acc);
      asm volatile("s_waitcnt vmcnt(0)" ::: "memory");
      __syncthreads();
      if (tid == 0)
        __hip_atomic_store(fB + (size_t)(m - 1) * 64 + ct, 1u,
                           __ATOMIC_RELAXED, __HIP_MEMORY_SCOPE_AGENT);
    }

  } else if (part == 2){
    // ---------- (c): h1 recurrence + ys ----------
    for (int m = 2; m <= SEQ + 1; ++m){
      int t1 = m - 2;
      if (w == 0){
        const unsigned* pBf = fB + (size_t)(m - 2) * 64 + ct;
        const unsigned* p1 = f1 + (size_t)(m - 3) * 64;
        int lim = 50000000;
        for (;;){
          unsigned vB = ald(pBf);
          unsigned v1 = (m >= 3) ? ald(p1 + lane) : 1u;
          if (__all((vB & v1) != 0) || !--lim) break;
          __builtin_amdgcn_s_sleep(1);
        }
      }
      __syncthreads();
      asm volatile("" ::: "memory");

      f32x4 acc[2][3] = {};
      if (t1 >= 1) gemm_ring(h1r + (size_t)((m - 3) & 1) * HSLOT, wbase, w, lane, acc);
      f32x4 g1[2][3];
      load_gi(gi1r + ((size_t)((m - 2) & 7) * 64 + ct) * 6144, w, lane, g1);

      f32x4 h[2];
      #pragma unroll
      for (int rt = 0; rt < 2; ++rt)
        #pragma unroll
        for (int q = 0; q < 4; ++q){
          float r = sigm(g1[rt][0][q] + acc[rt][0][q] + br_);
          float z = sigm(g1[rt][1][q] + acc[rt][1][q] + bz_);
          float n = tanh_(g1[rt][2][q] + bi_ + r * (acc[rt][2][q] + bh_));
          h[rt][q] = (1.0f - z) * n + z * hp[rt][q];
        }
      hp[0] = h[0]; hp[1] = h[1];

      publish_h(h1r + (size_t)((m - 2) & 1) * HSLOT, hvt[w], w, lane, ct, h);
      asm volatile("s_waitcnt vmcnt(0)" ::: "memory");
      __syncthreads();
      if (tid == 0)
        __hip_atomic_store(f1 + (size_t)(m - 2) * 64 + ct, 1u,
                           __ATOMIC_RELAXED, __HIP_MEMORY_SCOPE_AGENT);

      // ys writes (plain stores, off the flag path)
      #pragma unroll
      for (int rt = 0; rt < 2; ++rt)
        #pragma unroll
        for (int q = 0; q < 4; ++q)
          out[((size_t)t1 * BATCH + w*32 + rt*16 + kg*4 + q) * HID + col] = h[rt][q];
      if (t1 == SEQ - 1){
        #pragma unroll
        for (int rt = 0; rt < 2; ++rt)
          #pragma unroll
          for (int q = 0; q < 4; ++q)
            state[(size_t)(BATCH + w*32 + rt*16 + kg*4 + q) * HID + col] = hp[rt][q];
      }
    }

  } else {
    // ---------- (d): gi0 look-ahead ----------
    {   // prologue: gi0[0], no deps
      f32x4 acc[2][3] = {};
      gemm_x0(x0, wbase, w, lane, acc);
      store_gi(gi0r + (size_t)ct * 6144, w, lane, acc);
      asm volatile("s_waitcnt vmcnt(0)" ::: "memory");
      __syncthreads();
      if (tid == 0)
        __hip_atomic_store(fD + ct, 1u, __ATOMIC_RELAXED, __HIP_MEMORY_SCOPE_AGENT);
    }
    for (int m = 0; m <= SEQ - 2; ++m){
      int step = m + 1;
      if (w == 0 && m >= 7){
        const unsigned* p0 = f0 + (size_t)(m - 7) * 64 + ct;
        int lim = 50000000;
        while (!ald(p0) && --lim) __builtin_amdgcn_s_sleep(1);
      }
      __syncthreads();
      asm volatile("" ::: "memory");

      f32x4 acc[2][3] = {};
      gemm_x0(x0 + (size_t)step * BATCH * HID, wbase, w, lane, acc);
      store_gi(gi0r + ((size_t)(step & 7) * 64 + ct) * 6144, w, lane, acc);
      asm volatile("s_waitcnt vmcnt(0)" ::: "memory");
      __syncthreads();
      if (tid == 0)
        __hip_atomic_store(fD + (size_t)step * 64 + ct, 1u,
                           __ATOMIC_RELAXED, __HIP_MEMORY_SCOPE_AGENT);
    }
  }
}

// ---------------- launch ----------------

extern "C" void kernel_launch(void* const* d_in, const int* in_sizes, int n_in,
                              void* d_out, int out_size, void* d_ws, size_t ws_size,
                              hipStream_t stream){
  (void)in_sizes; (void)n_in; (void)out_size; (void)ws_size;
  const int*   src  = (const int*)  d_in[0];
  const float* embW = (const float*)d_in[1];
  const float* Wih  = (const float*)d_in[2];
  const float* Whh  = (const float*)d_in[3];
  const float* bih  = (const float*)d_in[4];
  const float* bhh  = (const float*)d_in[5];
  float* out = (float*)d_out;

  char* ws = (char*)d_ws;
  size_t off = 0;
  auto carve = [&](size_t bytes) -> void* {
    void* p = ws + off;
    off += (bytes + 255) & ~(size_t)255;
    return p;
  };
  const size_t WELEM = (size_t)2 * H3 * HID;
  const int NFLAG = 4 * MEGA * 64;               // all four flag arrays
  unsigned short* wihb = (unsigned short*)carve(WELEM * 2);
  unsigned short* whhb = (unsigned short*)carve(WELEM * 2);
  unsigned short* x0   = (unsigned short*)carve((size_t)SEQ*BATCH*HID*2);
  float*          gi0r = (float*)         carve((size_t)8 * GSLOT * 4);
  float*          gi1r = (float*)         carve((size_t)8 * GSLOT * 4);
  unsigned long long* h0r = (unsigned long long*)carve((size_t)4 * HSLOT * 8);
  unsigned long long* h1r = (unsigned long long*)carve((size_t)2 * HSLOT * 8);
  unsigned*       flags= (unsigned*)      carve((size_t)NFLAG * 4);
  unsigned* f0 = flags;
  unsigned* fB = flags + (size_t)MEGA * 64;
  unsigned* f1 = flags + (size_t)2 * MEGA * 64;
  unsigned* fD = flags + (size_t)3 * MEGA * 64;

  cvt_bf16<<<2048, 256, 0, stream>>>(Wih, wihb, (int)(WELEM/4));
  cvt_bf16<<<2048, 256, 0, stream>>>(Whh, whhb, (int)(WELEM/4));
  embed_gather<<<SEQ*BATCH, 256, 0, stream>>>(src, embW, x0);
  zero_u32<<<(NFLAG + 255)/256, 256, 0, stream>>>(flags, NFLAG);

  gru_fused<<<256, 256, 0, stream>>>(
      wihb,                       // Wih layer 0
      whhb,                       // Whh layer 0
      wihb + (size_t)H3*HID,      // Wih layer 1
      whhb + (size_t)H3*HID,      // Whh layer 1
      bih, bhh, x0,
      gi0r, gi1r, h0r, h1r, out,
      f0, fB, f1, fD);
}